// Round 3
// baseline (356.874 us; speedup 1.0000x reference)
//
#include <hip/hip_runtime.h>

#define N_RAYS 262144
#define N_PTS  64
#define FAR_DELTA 1e10f

#define THREADS 256
#define BLOCKS  2048                       // 8 blocks/CU on 256 CUs
#define NWAVES  (BLOCKS * (THREADS / 64))  // 8192 waves
#define ITERS   (N_RAYS / (NWAVES * 4))    // 8 iterations, 4 rays per wave-iter

__global__ __launch_bounds__(THREADS) void volume_render_kernel(
    const float* __restrict__ density,       // (N, 64, 1)
    const float* __restrict__ depth_values,  // (N, 64)
    const float* __restrict__ rays_feature,  // (N, 64, 3)
    float* __restrict__ out)                 // feature (N*3) then depth (N)
{
    const int lane = threadIdx.x & 63;
    const int wave = threadIdx.x >> 6;
    const int sub  = lane >> 4;        // which of the wave's 4 rays
    const int l    = lane & 15;        // lane within the 16-lane ray group
    const int gw   = blockIdx.x * (THREADS / 64) + wave;   // global wave id

    // ---- current-iteration registers (prefetched) ----
    float4 d, sg, fa, fb, fc;

    long ray = (long)gw * 4 + sub;     // iteration 0 ray for this lane
    {
        d  = ((const float4*)depth_values)[ray * 16 + l];
        sg = ((const float4*)density)[ray * 16 + l];
        const float4* fp = (const float4*)rays_feature + ray * 48 + l * 3;
        fa = fp[0]; fb = fp[1]; fc = fp[2];
    }

    #pragma unroll 1
    for (int it = 0; it < ITERS; ++it) {
        // ---- issue next iteration's loads FIRST: they stay in flight
        //      under this iteration's scan/exp dependency chain ----
        const long nray = ray + (long)NWAVES * 4;
        float4 nd, nsg, nfa, nfb, nfc;
        if (it + 1 < ITERS) {
            nd  = ((const float4*)depth_values)[nray * 16 + l];
            nsg = ((const float4*)density)[nray * 16 + l];
            const float4* nfp = (const float4*)rays_feature + nray * 48 + l * 3;
            nfa = nfp[0]; nfb = nfp[1]; nfc = nfp[2];
        }

        // ---- compute on the current registers ----
        // deltas: in-lane diffs + one boundary value from the next lane
        const float dnx = __shfl_down(d.x, 1, 16);
        const float dl0 = d.y - d.x;
        const float dl1 = d.z - d.y;
        const float dl2 = d.w - d.z;
        const float dl3 = (l == 15) ? FAR_DELTA : (dnx - d.w);

        // per-segment transmittance e_i = exp(-sigma_i * delta_i)
        const float e0 = __expf(-sg.x * dl0);
        const float e1 = __expf(-sg.y * dl1);
        const float e2 = __expf(-sg.z * dl2);
        const float e3 = __expf(-sg.w * dl3);   // lane 15: exp(-~1e10) -> 0

        // lane-local exclusive products q_i = prod_{j<i} e_j (q0 = 1)
        const float q1 = e0;
        const float q2 = q1 * e1;
        const float q3 = q2 * e2;

        // segmented (16-lane) exclusive multiplicative scan of lane totals
        float ptot = q3 * e3;
        #pragma unroll
        for (int off = 1; off < 16; off <<= 1) {
            float t = __shfl_up(ptot, off, 16);
            if (l >= off) ptot *= t;
        }
        float p_exc = __shfl_up(ptot, 1, 16);  // lane 15's total never consumed
        if (l == 0) p_exc = 1.0f;

        // weights w_i = T_i * (1 - e_i), T_i = p_exc * q_i
        const float w0 = p_exc *      (1.0f - e0);
        const float w1 = p_exc * q1 * (1.0f - e1);
        const float w2 = p_exc * q2 * (1.0f - e2);
        const float w3 = p_exc * q3 * (1.0f - e3);

        // fully lane-local weighted feature / depth partials
        float fx = w0*fa.x + w1*fa.w + w2*fb.z + w3*fc.y;
        float fy = w0*fa.y + w1*fb.x + w2*fb.w + w3*fc.z;
        float fz = w0*fa.z + w1*fb.y + w2*fc.x + w3*fc.w;
        float wd = w0*d.x  + w1*d.y  + w2*d.z  + w3*d.w;

        // 16-lane butterfly reduction (4 steps x 4 accumulators)
        #pragma unroll
        for (int off = 8; off > 0; off >>= 1) {
            fx += __shfl_xor(fx, off, 16);
            fy += __shfl_xor(fy, off, 16);
            fz += __shfl_xor(fz, off, 16);
            wd += __shfl_xor(wd, off, 16);
        }

        // epilogue: lanes 0..2 of each group store xyz (12 consecutive
        // floats per wave), lane 3 stores depth (4 consecutive floats)
        if (l < 3) {
            const float v = (l == 0) ? fx : ((l == 1) ? fy : fz);
            out[ray * 3 + l] = v;
        } else if (l == 3) {
            out[(long)N_RAYS * 3 + ray] = wd;
        }

        // ---- rotate prefetched registers ----
        d = nd; sg = nsg; fa = nfa; fb = nfb; fc = nfc;
        ray = nray;
    }
}

extern "C" void kernel_launch(void* const* d_in, const int* in_sizes, int n_in,
                              void* d_out, int out_size, void* d_ws, size_t ws_size,
                              hipStream_t stream) {
    const float* density      = (const float*)d_in[0];
    const float* depth_values = (const float*)d_in[1];
    const float* rays_feature = (const float*)d_in[2];
    float* out = (float*)d_out;

    volume_render_kernel<<<BLOCKS, THREADS, 0, stream>>>(
        density, depth_values, rays_feature, out);
}

// Round 4
// 354.867 us; speedup vs baseline: 1.0057x; 1.0057x over previous
//
#include <hip/hip_runtime.h>

#define N_RAYS 262144
#define N_PTS  64
#define FAR_DELTA 1e10f
#define THREADS 256
// 256 threads = 4 waves; each wave renders 8 rays as TWO 4-ray quads
// (16 lanes/ray, 4 samples/lane). All 10 loads issue before any compute,
// so quad B's 5 loads stay in flight under quad A's dependency chain.
#define RAYS_PER_BLOCK 32
#define BLOCKS (N_RAYS / RAYS_PER_BLOCK)   // 8192

__device__ __forceinline__ void render_quad(
    const float4 d, const float4 sg,
    const float4 fa, const float4 fb, const float4 fc,
    const int l, const long ray, float* __restrict__ out)
{
    // deltas: in-lane diffs + one boundary value from the next lane
    const float dnx = __shfl_down(d.x, 1, 16);
    const float dl0 = d.y - d.x;
    const float dl1 = d.z - d.y;
    const float dl2 = d.w - d.z;
    const float dl3 = (l == 15) ? FAR_DELTA : (dnx - d.w);

    // per-segment transmittance e_i = exp(-sigma_i * delta_i)
    const float e0 = __expf(-sg.x * dl0);
    const float e1 = __expf(-sg.y * dl1);
    const float e2 = __expf(-sg.z * dl2);
    const float e3 = __expf(-sg.w * dl3);   // lane 15: exp(-~1e10) -> 0, fine

    // lane-local exclusive products q_i = prod_{j<i} e_j (q0 = 1)
    const float q1 = e0;
    const float q2 = q1 * e1;
    const float q3 = q2 * e2;

    // segmented (16-lane) exclusive multiplicative scan of lane totals
    float ptot = q3 * e3;
    #pragma unroll
    for (int off = 1; off < 16; off <<= 1) {
        float t = __shfl_up(ptot, off, 16);
        if (l >= off) ptot *= t;
    }
    float p_exc = __shfl_up(ptot, 1, 16);   // lane 15's total never consumed
    if (l == 0) p_exc = 1.0f;

    // weights w_i = T_i * (1 - e_i), T_i = p_exc * q_i
    const float w0 = p_exc *      (1.0f - e0);
    const float w1 = p_exc * q1 * (1.0f - e1);
    const float w2 = p_exc * q2 * (1.0f - e2);
    const float w3 = p_exc * q3 * (1.0f - e3);

    // fully lane-local weighted feature / depth partials
    float fx = w0*fa.x + w1*fa.w + w2*fb.z + w3*fc.y;
    float fy = w0*fa.y + w1*fb.x + w2*fb.w + w3*fc.z;
    float fz = w0*fa.z + w1*fb.y + w2*fc.x + w3*fc.w;
    float wd = w0*d.x  + w1*d.y  + w2*d.z  + w3*d.w;

    // 16-lane butterfly reduction (4 steps x 4 accumulators)
    #pragma unroll
    for (int off = 8; off > 0; off >>= 1) {
        fx += __shfl_xor(fx, off, 16);
        fy += __shfl_xor(fy, off, 16);
        fz += __shfl_xor(fz, off, 16);
        wd += __shfl_xor(wd, off, 16);
    }

    // epilogue: lanes 0..2 of each group store xyz, lane 3 stores depth
    if (l < 3) {
        const float v = (l == 0) ? fx : ((l == 1) ? fy : fz);
        out[ray * 3 + l] = v;
    } else if (l == 3) {
        out[(long)N_RAYS * 3 + ray] = wd;
    }
}

__global__ __launch_bounds__(THREADS) void volume_render_kernel(
    const float* __restrict__ density,       // (N, 64, 1)
    const float* __restrict__ depth_values,  // (N, 64)
    const float* __restrict__ rays_feature,  // (N, 64, 3)
    float* __restrict__ out)                 // feature (N*3) then depth (N)
{
    const int lane = threadIdx.x & 63;
    const int wave = threadIdx.x >> 6;
    const int sub  = lane >> 4;        // which of the quad's 4 rays
    const int l    = lane & 15;        // lane within the 16-lane ray group
    const long gw  = (long)blockIdx.x * 4 + wave;
    const long rayA = gw * 8 + sub;
    const long rayB = rayA + 4;

    // ---- all 10 loads issued up front; no compute dependence between
    //      them, so all 10 lines-worth stay in flight together ----
    const float4 dA  = ((const float4*)depth_values)[rayA * 16 + l];
    const float4 sgA = ((const float4*)density)[rayA * 16 + l];
    const float4* fpA = (const float4*)rays_feature + rayA * 48 + l * 3;
    const float4 faA = fpA[0];
    const float4 fbA = fpA[1];
    const float4 fcA = fpA[2];

    const float4 dB  = ((const float4*)depth_values)[rayB * 16 + l];
    const float4 sgB = ((const float4*)density)[rayB * 16 + l];
    const float4* fpB = (const float4*)rays_feature + rayB * 48 + l * 3;
    const float4 faB = fpB[0];
    const float4 fbB = fpB[1];
    const float4 fcB = fpB[2];

    // compute quad A while quad B's loads are still in flight
    render_quad(dA, sgA, faA, fbA, fcA, l, rayA, out);
    render_quad(dB, sgB, faB, fbB, fcB, l, rayB, out);
}

extern "C" void kernel_launch(void* const* d_in, const int* in_sizes, int n_in,
                              void* d_out, int out_size, void* d_ws, size_t ws_size,
                              hipStream_t stream) {
    const float* density      = (const float*)d_in[0];
    const float* depth_values = (const float*)d_in[1];
    const float* rays_feature = (const float*)d_in[2];
    float* out = (float*)d_out;

    volume_render_kernel<<<BLOCKS, THREADS, 0, stream>>>(
        density, depth_values, rays_feature, out);
}